// Round 1
// baseline (934.806 us; speedup 1.0000x reference)
//
#include <hip/hip_runtime.h>

#define BATCH 256
#define TSTEPS 1024
#define NIN 128
#define NL 64
#define NH 128
#define NOUT 32

// LDS layout (floats):
//   s chunk:  [0, 4096)      32 timesteps x 128
//   hidden:   [4096, 4224)   128
//   z:        [4224, 4288)   64
//   u:        [4288, 4352)   64
#define HID_OFF 4096
#define Z_OFF   4224
#define U_OFF   4288
#define HID4    (HID_OFF/4)
#define Z4      (Z_OFF/4)

__launch_bounds__(256, 1)
__global__ void plrnn_scan_kernel(const float* __restrict__ input,
                                  const float* __restrict__ A,
                                  const float* __restrict__ W1,
                                  const float* __restrict__ W2,
                                  const float* __restrict__ h1,
                                  const float* __restrict__ h2,
                                  const float* __restrict__ C,
                                  const float* __restrict__ Wout,
                                  const float* __restrict__ bout,
                                  float* __restrict__ out) {
    __shared__ float smem[4352];
    float4* smem4 = (float4*)smem;

    const int tid = threadIdx.x;
    const int b   = blockIdx.x;

    // ---- persistent weight registers ----
    float wr[64];   // phase A weights: W2 row (tid<128) or C half-row (tid>=128)
    float w1r[32];  // phase B weights: W1 quarter-row
    float h2r = 0.f;

    const int l2 = tid >> 2;      // phase B output index (0..63)
    const int q  = tid & 3;       // phase B quarter (0..3)

    if (tid < NH) {
        // wave 0/1: full W2 row for hidden h = tid
        #pragma unroll
        for (int k = 0; k < 16; ++k) {
            float4 v = ((const float4*)W2)[tid * 16 + k];
            wr[4*k+0] = v.x; wr[4*k+1] = v.y; wr[4*k+2] = v.z; wr[4*k+3] = v.w;
        }
        h2r = h2[tid];
    } else {
        // wave 2/3: half C row for u output lu, half = uhalf
        int j = tid - NH;
        int lu = j >> 1, half = j & 1;
        #pragma unroll
        for (int k = 0; k < 16; ++k) {
            float4 v = ((const float4*)C)[lu * 32 + half * 16 + k];
            wr[4*k+0] = v.x; wr[4*k+1] = v.y; wr[4*k+2] = v.z; wr[4*k+3] = v.w;
        }
    }
    #pragma unroll
    for (int k = 0; k < 8; ++k) {
        float4 v = ((const float4*)W1)[l2 * 32 + q * 8 + k];
        w1r[4*k+0] = v.x; w1r[4*k+1] = v.y; w1r[4*k+2] = v.z; w1r[4*k+3] = v.w;
    }
    const float ar  = A[l2];
    const float h1r = h1[l2];

    const int uhalf = (tid >= NH) ? ((tid - NH) & 1) : 0;
    const int ul    = (tid >= NH) ? ((tid - NH) >> 1) : 0;

    // init z = 0
    float zreg = 0.f;                 // live in lane q==0 of each quad (tid = 4*l2)
    if (tid < NL) smem[Z_OFF + tid] = 0.f;
    __syncthreads();

    const float4* in4 = (const float4*)input + (size_t)b * (TSTEPS * NIN / 4);

    for (int t0 = 0; t0 < TSTEPS; t0 += 32) {
        // stage 32 timesteps of s into LDS (16 KB), coalesced float4
        #pragma unroll
        for (int k = 0; k < 4; ++k) {
            smem4[k * 256 + tid] = in4[t0 * 32 + k * 256 + tid];
        }
        __syncthreads();

        for (int tt = 0; tt < 32; ++tt) {
            // ---------------- PHASE A ----------------
            // waves 0/1: hidden[h] = relu(W2[h,:]·z + h2[h])   (full dot-64)
            // waves 2/3: u[l] partial = C[l, half*64:...]·s     (half dot-64)
            const int abase = (tid < NH) ? Z4 : (tt * 32 + uhalf * 16);
            float a0 = 0.f, a1 = 0.f, a2 = 0.f, a3 = 0.f;
            #pragma unroll
            for (int k = 0; k < 16; ++k) {
                float4 o = smem4[abase + k];
                a0 += wr[4*k+0] * o.x;
                a1 += wr[4*k+1] * o.y;
                a2 += wr[4*k+2] * o.z;
                a3 += wr[4*k+3] * o.w;
            }
            float acc = (a0 + a1) + (a2 + a3);
            if (tid < NH) {
                float hv = fmaxf(acc + h2r, 0.f);
                smem[HID_OFF + tid] = hv;
            } else {
                acc += __shfl_xor(acc, 1, 64);
                if (uhalf == 0) smem[U_OFF + ul] = acc;
            }
            __syncthreads();

            // ---------------- PHASE B ----------------
            // all threads: z'[l2] partial = W1[l2, q*32:...]·hidden (quarter dot-32)
            float c0 = 0.f, c1 = 0.f, c2 = 0.f, c3 = 0.f;
            #pragma unroll
            for (int k = 0; k < 8; ++k) {
                float4 o = smem4[HID4 + q * 8 + k];
                c0 += w1r[4*k+0] * o.x;
                c1 += w1r[4*k+1] * o.y;
                c2 += w1r[4*k+2] * o.z;
                c3 += w1r[4*k+3] * o.w;
            }
            float acc2 = (c0 + c1) + (c2 + c3);
            acc2 += __shfl_xor(acc2, 1, 64);
            acc2 += __shfl_xor(acc2, 2, 64);
            if (q == 0) {
                float u  = smem[U_OFF + l2];
                float zn = zreg * ar + acc2 + h1r + u;
                zn = fminf(fmaxf(zn, -5.f), 5.f);
                zreg = zn;
                smem[Z_OFF + l2] = zn;
            }
            __syncthreads();
        }
    }

    // epilogue: out[b,o] = Wout[o,:]·z + bout[o]
    if (tid < NOUT) {
        float acc = bout[tid];
        #pragma unroll
        for (int l = 0; l < NL; ++l)
            acc += Wout[tid * NL + l] * smem[Z_OFF + l];
        out[b * NOUT + tid] = acc;
    }
}

extern "C" void kernel_launch(void* const* d_in, const int* in_sizes, int n_in,
                              void* d_out, int out_size, void* d_ws, size_t ws_size,
                              hipStream_t stream) {
    const float* input = (const float*)d_in[0];
    const float* A     = (const float*)d_in[1];
    const float* W1    = (const float*)d_in[2];
    const float* W2    = (const float*)d_in[3];
    const float* h1    = (const float*)d_in[4];
    const float* h2    = (const float*)d_in[5];
    const float* C     = (const float*)d_in[6];
    const float* Wout  = (const float*)d_in[7];
    const float* bout  = (const float*)d_in[8];
    float* out = (float*)d_out;

    plrnn_scan_kernel<<<dim3(BATCH), dim3(256), 0, stream>>>(
        input, A, W1, W2, h1, h2, C, Wout, bout, out);
}

// Round 2
// 933.320 us; speedup vs baseline: 1.0016x; 1.0016x over previous
//
#include <hip/hip_runtime.h>

#define BATCH 256
#define TSTEPS 1024
#define NIN 128
#define NL 64
#define NH 128
#define NOUT 32

// ---------------------------------------------------------------------------
// Pass 0: transpose C [64][128] -> Ct [128][64]  (ws[0 .. 8192))
// ---------------------------------------------------------------------------
__global__ void transpose_C_kernel(const float* __restrict__ C,
                                   float* __restrict__ Ct) {
    int gid = blockIdx.x * 256 + threadIdx.x;   // 8192 elements
    int l = gid & 63;
    int i = gid >> 6;
    Ct[gid] = C[l * NIN + i];   // Ct[i][l] = C[l][i]
}

// ---------------------------------------------------------------------------
// Pass 1: u[b,t,l] = sum_i C[l,i] * s[b,t,i]
// Grid: 256 batches x 16 chunks of 64 rows; block = 1 wave (64 threads).
// lane = row (t within chunk). Weights Ct[i][:] are wave-uniform -> SGPR
// broadcast (s_load), operand s per-lane from LDS. 64 FMA : 1 ds_read.
// ---------------------------------------------------------------------------
#define ROWS 64
#define SSTRIDE 132   // floats; 132*4B = 528B, 16B-aligned rows
__launch_bounds__(64, 1)
__global__ void ugemm_kernel(const float* __restrict__ input,
                             const float* __restrict__ Ct,
                             float* __restrict__ u) {
    __shared__ float s_lds[ROWS * SSTRIDE];
    float4* lds4 = (float4*)s_lds;

    const int lane  = threadIdx.x;
    const int b     = blockIdx.x >> 4;
    const int chunk = blockIdx.x & 15;
    const long rowbase = (long)b * TSTEPS + chunk * ROWS;

    // stage 64 rows x 128 floats, coalesced float4
    const float4* in4 = (const float4*)input + rowbase * (NIN / 4);
    #pragma unroll
    for (int j = 0; j < 32; ++j) {
        int e = j * 64 + lane;          // float4 index within tile
        int r = e >> 5, c4 = e & 31;    // 32 float4 per row
        lds4[r * (SSTRIDE / 4) + c4] = in4[e];
    }
    __syncthreads();

    float acc[64];
    #pragma unroll
    for (int l = 0; l < 64; ++l) acc[l] = 0.f;

    const float* srow = &s_lds[lane * SSTRIDE];
    #pragma unroll 2
    for (int i = 0; i < NIN; ++i) {
        float sv = srow[i];
        const float* crow = &Ct[i * NL];   // wave-uniform -> s_load
        #pragma unroll
        for (int l = 0; l < 64; ++l)
            acc[l] = fmaf(crow[l], sv, acc[l]);
    }

    float4* u4 = (float4*)u + (rowbase + lane) * (NL / 4);
    #pragma unroll
    for (int k = 0; k < 16; ++k)
        u4[k] = make_float4(acc[4*k], acc[4*k+1], acc[4*k+2], acc[4*k+3]);
}

// ---------------------------------------------------------------------------
// Pass 2: the scan. 1 block (4 waves) per batch.
// Phase A: hidden[128]=relu(W2@z+h2): 2 lanes/output, half-dot-32.
// Phase B: z'[64]=A*z+W1@hidden+h1+u: 4 lanes/output, quarter-dot-32,
//          k-rotated reads (conflict-free), u prefetched from global.
// ---------------------------------------------------------------------------
__launch_bounds__(256, 1)
__global__ void plrnn_scan_kernel(const float* __restrict__ A,
                                  const float* __restrict__ W1,
                                  const float* __restrict__ W2,
                                  const float* __restrict__ h1,
                                  const float* __restrict__ h2,
                                  const float* __restrict__ u,
                                  const float* __restrict__ Wout,
                                  const float* __restrict__ bout,
                                  float* __restrict__ out) {
    __shared__ float4 sm4[48];          // z: [0,16) , hidden: [16,48)
    float* zbuf = (float*)sm4;          // 64 floats
    float4* hbuf4 = sm4 + 16;           // 128 floats

    const int tid  = threadIdx.x;
    const int b    = blockIdx.x;
    const int w    = tid >> 6;
    const int l    = tid & 63;

    // ---- phase A assignment: output hA, half of the dot ----
    const int hA   = w * 32 + (l >> 1);
    const int half = l & 1;
    float w2r[32];
    #pragma unroll
    for (int k = 0; k < 8; ++k) {
        float4 v = ((const float4*)W2)[hA * 16 + half * 8 + k];
        w2r[4*k+0] = v.x; w2r[4*k+1] = v.y; w2r[4*k+2] = v.z; w2r[4*k+3] = v.w;
    }
    const float h2r = h2[hA];

    // ---- phase B assignment: output zl, quarter q ----
    const int zl = w * 16 + (l & 15);
    const int q  = l >> 4;
    float w1r[32];
    #pragma unroll
    for (int k = 0; k < 8; ++k) {
        float4 v = ((const float4*)W1)[zl * 32 + q * 8 + k];
        w1r[4*k+0] = v.x; w1r[4*k+1] = v.y; w1r[4*k+2] = v.z; w1r[4*k+3] = v.w;
    }
    const float ar  = A[zl];
    const float h1r = h1[zl];

    float zreg = 0.f;
    if (tid < NL) zbuf[tid] = 0.f;
    __syncthreads();

    const float* up = u + ((long)b * TSTEPS) * NL + zl;
    float ucur = (q == 0) ? up[0] : 0.f;

    for (int t = 0; t < TSTEPS; ++t) {
        // prefetch next step's u (latency hidden under both phases)
        float unext = (q == 0 && t + 1 < TSTEPS) ? up[(t + 1) * NL] : 0.f;

        // ---------------- PHASE A ----------------
        float a0 = 0.f, a1 = 0.f, a2 = 0.f, a3 = 0.f;
        const float4* zb4 = sm4 + half * 8;
        #pragma unroll
        for (int k = 0; k < 8; ++k) {
            float4 o = zb4[k];
            a0 = fmaf(w2r[4*k+0], o.x, a0);
            a1 = fmaf(w2r[4*k+1], o.y, a1);
            a2 = fmaf(w2r[4*k+2], o.z, a2);
            a3 = fmaf(w2r[4*k+3], o.w, a3);
        }
        float acc = (a0 + a1) + (a2 + a3);
        acc += __shfl_xor(acc, 1, 64);
        if (half == 0) {
            float hv = fmaxf(acc + h2r, 0.f);
            ((float*)hbuf4)[hA] = hv;
        }
        __syncthreads();

        // ---------------- PHASE B ----------------
        float c0 = 0.f, c1 = 0.f, c2 = 0.f, c3 = 0.f;
        #pragma unroll
        for (int k = 0; k < 8; ++k) {
            int kk = (k + 2 * q) & 7;            // bank-group rotation
            float4 o = hbuf4[q * 8 + kk];
            c0 = fmaf(w1r[4*kk+0], o.x, c0);
            c1 = fmaf(w1r[4*kk+1], o.y, c1);
            c2 = fmaf(w1r[4*kk+2], o.z, c2);
            c3 = fmaf(w1r[4*kk+3], o.w, c3);
        }
        float acc2 = (c0 + c1) + (c2 + c3);
        acc2 += __shfl_xor(acc2, 16, 64);
        acc2 += __shfl_xor(acc2, 32, 64);
        if (q == 0) {
            float zn = zreg * ar + acc2 + h1r + ucur;
            zn = fminf(fmaxf(zn, -5.f), 5.f);
            zreg = zn;
            zbuf[zl] = zn;
        }
        ucur = unext;
        __syncthreads();
    }

    // epilogue: out[b,o] = Wout[o,:]·z + bout[o]
    if (tid < NOUT) {
        float acc = bout[tid];
        #pragma unroll
        for (int j = 0; j < NL; ++j)
            acc = fmaf(Wout[tid * NL + j], zbuf[j], acc);
        out[b * NOUT + tid] = acc;
    }
}

extern "C" void kernel_launch(void* const* d_in, const int* in_sizes, int n_in,
                              void* d_out, int out_size, void* d_ws, size_t ws_size,
                              hipStream_t stream) {
    const float* input = (const float*)d_in[0];
    const float* A     = (const float*)d_in[1];
    const float* W1    = (const float*)d_in[2];
    const float* W2    = (const float*)d_in[3];
    const float* h1    = (const float*)d_in[4];
    const float* h2    = (const float*)d_in[5];
    const float* C     = (const float*)d_in[6];
    const float* Wout  = (const float*)d_in[7];
    const float* bout  = (const float*)d_in[8];
    float* out = (float*)d_out;

    float* ws  = (float*)d_ws;
    float* Ct  = ws;            // 8192 floats
    float* u   = ws + 8192;     // 256*1024*64 floats = 64 MB

    transpose_C_kernel<<<dim3(32), dim3(256), 0, stream>>>(C, Ct);
    ugemm_kernel<<<dim3(BATCH * 16), dim3(64), 0, stream>>>(input, Ct, u);
    plrnn_scan_kernel<<<dim3(BATCH), dim3(256), 0, stream>>>(
        A, W1, W2, h1, h2, u, Wout, bout, out);
}